// Round 1
// baseline (513.554 us; speedup 1.0000x reference)
//
#include <hip/hip_runtime.h>

#define NATOMS 4096
#define NF (3 * NATOMS)          // 12288 force components
#define CUTOFF_F 12.0f

// ---------------------------------------------------------------------------
// Kernel 1: grid-stride over pairs. Per-block LDS force accumulator (48 KB),
// per-thread energy accumulator -> wave shuffle reduce -> block reduce.
// USE_WS: write per-block partials to workspace (deterministic 2-pass).
// else : global atomics into d_out (fallback if ws too small).
// ---------------------------------------------------------------------------
template <bool USE_WS>
__global__ __launch_bounds__(1024) void pair_kernel(
    const float* __restrict__ dist,
    const float* __restrict__ vec,
    const float* __restrict__ Bc,
    const int2* __restrict__ idx,
    const float* __restrict__ forces_in,
    int npairs,
    float* __restrict__ ws_f,   // [gridDim.x][NF]
    float* __restrict__ ws_e,   // [gridDim.x]
    float* __restrict__ out)    // [1 + NF] (fallback path)
{
    __shared__ float facc[NF];
    __shared__ float we[16];

    for (int i = threadIdx.x; i < NF; i += blockDim.x) facc[i] = 0.0f;
    __syncthreads();

    float e = 0.0f;
    int tid    = blockIdx.x * blockDim.x + threadIdx.x;
    int stride = gridDim.x * blockDim.x;

    for (int p = tid; p < npairs; p += stride) {
        int2 ab = idx[p];
        float d = dist[ab.x * NATOMS + ab.y];
        if (d <= CUTOFF_F) {
            float b    = Bc[p];
            float invd = 1.0f / d;
            float i2   = invd * invd;
            float w    = b * i2 * i2 * i2;   // B * d^-6
            e += w;
            float f = -6.0f * w * invd;      // -6 B d^-7
            size_t base = (size_t)(ab.x * NATOMS + ab.y) * 3;
            float fx = f * vec[base + 0];
            float fy = f * vec[base + 1];
            float fz = f * vec[base + 2];
            atomicAdd(&facc[3 * ab.x + 0],  fx);
            atomicAdd(&facc[3 * ab.x + 1],  fy);
            atomicAdd(&facc[3 * ab.x + 2],  fz);
            atomicAdd(&facc[3 * ab.y + 0], -fx);
            atomicAdd(&facc[3 * ab.y + 1], -fy);
            atomicAdd(&facc[3 * ab.y + 2], -fz);
        }
    }
    __syncthreads();

    // ---- flush per-block force partial ----
    if (USE_WS) {
        float* dst = ws_f + (size_t)blockIdx.x * NF;
        for (int i = threadIdx.x; i < NF; i += blockDim.x) dst[i] = facc[i];
    } else {
        for (int i = threadIdx.x; i < NF; i += blockDim.x) {
            float v = facc[i];
            if (blockIdx.x == 0) v += forces_in[i];
            atomicAdd(&out[1 + i], v);
        }
    }

    // ---- energy block reduction ----
    for (int off = 32; off > 0; off >>= 1) e += __shfl_down(e, off, 64);
    int wid  = threadIdx.x >> 6;
    int lane = threadIdx.x & 63;
    if (lane == 0) we[wid] = e;
    __syncthreads();
    if (threadIdx.x == 0) {
        float s = 0.0f;
        int nw = blockDim.x >> 6;
        for (int w = 0; w < nw; ++w) s += we[w];
        if (USE_WS) ws_e[blockIdx.x] = s;
        else        atomicAdd(&out[0], s);
    }
}

// ---------------------------------------------------------------------------
// Kernel 2: deterministic reduction of per-block partials.
// Thread i -> forces component i (coalesced across blocks of ws_f).
// First wave of block 0 also reduces the per-block energies.
// ---------------------------------------------------------------------------
__global__ __launch_bounds__(256) void reduce_kernel(
    const float* __restrict__ ws_f,
    const float* __restrict__ ws_e,
    const float* __restrict__ forces_in,
    float* __restrict__ out,
    int nb)
{
    int i = blockIdx.x * 256 + threadIdx.x;
    if (i < NF) {
        float s = forces_in[i];
        for (int b = 0; b < nb; ++b) s += ws_f[(size_t)b * NF + i];
        out[1 + i] = s;
    }
    if (blockIdx.x == 0 && threadIdx.x < 64) {
        float s = 0.0f;
        for (int b = threadIdx.x; b < nb; b += 64) s += ws_e[b];
        for (int off = 32; off > 0; off >>= 1) s += __shfl_down(s, off, 64);
        if (threadIdx.x == 0) out[0] = s;
    }
}

extern "C" void kernel_launch(void* const* d_in, const int* in_sizes, int n_in,
                              void* d_out, int out_size, void* d_ws, size_t ws_size,
                              hipStream_t stream) {
    const float* dist      = (const float*)d_in[0];  // (4096,4096) f32
    const float* vec       = (const float*)d_in[1];  // (4096,4096,3) f32
    const float* forces_in = (const float*)d_in[2];  // (4096,3) f32 zeros
    const float* Bc        = (const float*)d_in[3];  // (4M,) f32
    const int2*  idx       = (const int2*)d_in[4];   // (4M,2) i32
    float* out = (float*)d_out;                      // [0]=energy, [1..12288]=forces

    const int npairs = in_sizes[3];                  // 4,000,000
    const int NB = 512;                              // 2 blocks/CU * 256 CUs
    const int NT = 1024;                             // 32 waves/CU occupancy

    size_t need = (size_t)NB * NF * sizeof(float) + NB * sizeof(float);
    if (ws_size >= need) {
        float* ws_f = (float*)d_ws;
        float* ws_e = ws_f + (size_t)NB * NF;
        pair_kernel<true><<<NB, NT, 0, stream>>>(dist, vec, Bc, idx, forces_in,
                                                 npairs, ws_f, ws_e, out);
        reduce_kernel<<<(NF + 255) / 256, 256, 0, stream>>>(ws_f, ws_e, forces_in, out, NB);
    } else {
        hipMemsetAsync(d_out, 0, (size_t)(1 + NF) * sizeof(float), stream);
        pair_kernel<false><<<NB, NT, 0, stream>>>(dist, vec, Bc, idx, forces_in,
                                                  npairs, nullptr, nullptr, out);
    }
}

// Round 4
// 406.882 us; speedup vs baseline: 1.2622x; 1.2622x over previous
//
#include <hip/hip_runtime.h>

#define NATOMS 4096
#define NF (3 * NATOMS)          // 12288 force components
#define CUTOFF_F 12.0f
#define NB 512                   // pair-kernel blocks (2/CU)
#define RSPLIT 16                // reduction: slices over the NB partials
#define CPB (NF / 256)           // 48 component-blocks per slice

// ---------------------------------------------------------------------------
// Kernel 1: grid-stride over pairs, 2-way unrolled for MLP. Per-block LDS
// force accumulator (48 KB) -> per-block partial in ws. Per-thread energy ->
// shuffle reduce -> ws_e.
// ---------------------------------------------------------------------------
__device__ __forceinline__ void do_pair(int2 ab, float b, float d,
                                        float* facc, float& e,
                                        const float* __restrict__ vec) {
    if (d <= CUTOFF_F) {
        float invd = 1.0f / d;
        float i2   = invd * invd;
        float w    = b * i2 * i2 * i2;   // B * d^-6
        e += w;
        float f = -6.0f * w * invd;      // -6 B d^-7
        size_t base = (size_t)(ab.x * NATOMS + ab.y) * 3;
        float fx = f * vec[base + 0];
        float fy = f * vec[base + 1];
        float fz = f * vec[base + 2];
        atomicAdd(&facc[3 * ab.x + 0],  fx);
        atomicAdd(&facc[3 * ab.x + 1],  fy);
        atomicAdd(&facc[3 * ab.x + 2],  fz);
        atomicAdd(&facc[3 * ab.y + 0], -fx);
        atomicAdd(&facc[3 * ab.y + 1], -fy);
        atomicAdd(&facc[3 * ab.y + 2], -fz);
    }
}

__global__ __launch_bounds__(1024) void pair_kernel(
    const float* __restrict__ dist,
    const float* __restrict__ vec,
    const float* __restrict__ Bc,
    const int2* __restrict__ idx,
    int npairs,
    float* __restrict__ ws_f,   // [NB][NF]
    float* __restrict__ ws_e)   // [NB]
{
    __shared__ float facc[NF];
    __shared__ float we[16];

    for (int i = threadIdx.x; i < NF; i += blockDim.x) facc[i] = 0.0f;
    __syncthreads();

    float e = 0.0f;
    int tid    = blockIdx.x * blockDim.x + threadIdx.x;
    int stride = gridDim.x * blockDim.x;

    for (int p = tid; p < npairs; p += 2 * stride) {
        int p2 = p + stride;
        bool h2 = p2 < npairs;
        // issue both dependency chains' loads up front
        int2  ab1 = idx[p];
        float b1  = Bc[p];
        int2  ab2 = h2 ? idx[p2] : make_int2(0, 0);
        float b2  = h2 ? Bc[p2] : 0.0f;       // b=0 => w=0, f=0: harmless
        float d1  = dist[ab1.x * NATOMS + ab1.y];
        float d2  = dist[ab2.x * NATOMS + ab2.y];
        do_pair(ab1, b1, d1, facc, e, vec);
        do_pair(ab2, b2, d2, facc, e, vec);
    }
    __syncthreads();

    // ---- flush per-block force partial (coalesced) ----
    float* dst = ws_f + (size_t)blockIdx.x * NF;
    for (int i = threadIdx.x; i < NF; i += blockDim.x) dst[i] = facc[i];

    // ---- energy block reduction ----
    for (int off = 32; off > 0; off >>= 1) e += __shfl_down(e, off, 64);
    int wid  = threadIdx.x >> 6;
    int lane = threadIdx.x & 63;
    if (lane == 0) we[wid] = e;
    __syncthreads();
    if (threadIdx.x == 0) {
        float s = 0.0f;
        int nw = blockDim.x >> 6;
        for (int w = 0; w < nw; ++w) s += we[w];
        ws_e[blockIdx.x] = s;
    }
}

// ---------------------------------------------------------------------------
// Kernel 2: parallel reduction of per-block partials.
// grid = RSPLIT * CPB blocks; block (slice, cb) sums NB/RSPLIT partials for
// components [cb*256, cb*256+256) and atomically adds into d_out (out was
// zeroed by memset; 16 same-address adds per component).
// ---------------------------------------------------------------------------
__global__ __launch_bounds__(256) void reduce_kernel(
    const float* __restrict__ ws_f,
    const float* __restrict__ ws_e,
    const float* __restrict__ forces_in,
    float* __restrict__ out)
{
    int slice = blockIdx.x / CPB;
    int cb    = blockIdx.x % CPB;
    int i     = cb * 256 + threadIdx.x;
    int b0    = slice * (NB / RSPLIT);
    int b1    = b0 + (NB / RSPLIT);

    float s = (slice == 0) ? forces_in[i] : 0.0f;
    #pragma unroll 4
    for (int b = b0; b < b1; ++b) s += ws_f[(size_t)b * NF + i];
    atomicAdd(&out[1 + i], s);

    // energy: one wave, deterministic, single writer
    if (blockIdx.x == 0 && threadIdx.x < 64) {
        float se = 0.0f;
        for (int b = threadIdx.x; b < NB; b += 64) se += ws_e[b];
        for (int off = 32; off > 0; off >>= 1) se += __shfl_down(se, off, 64);
        if (threadIdx.x == 0) out[0] = se;
    }
}

extern "C" void kernel_launch(void* const* d_in, const int* in_sizes, int n_in,
                              void* d_out, int out_size, void* d_ws, size_t ws_size,
                              hipStream_t stream) {
    const float* dist      = (const float*)d_in[0];  // (4096,4096) f32
    const float* vec       = (const float*)d_in[1];  // (4096,4096,3) f32
    const float* forces_in = (const float*)d_in[2];  // (4096,3) f32 zeros
    const float* Bc        = (const float*)d_in[3];  // (4M,) f32
    const int2*  idx       = (const int2*)d_in[4];   // (4M,2) i32
    float* out = (float*)d_out;                      // [0]=energy, [1..NF]=forces

    const int npairs = in_sizes[3];                  // 4,000,000

    float* ws_f = (float*)d_ws;
    float* ws_e = ws_f + (size_t)NB * NF;

    hipMemsetAsync(d_out, 0, (size_t)(1 + NF) * sizeof(float), stream);
    pair_kernel<<<NB, 1024, 0, stream>>>(dist, vec, Bc, idx, npairs, ws_f, ws_e);
    reduce_kernel<<<RSPLIT * CPB, 256, 0, stream>>>(ws_f, ws_e, forces_in, out);
}